// Round 9
// baseline (122.877 us; speedup 1.0000x reference)
//
#include <hip/hip_runtime.h>

#define N_NODES 10000
#define N_EDGES 640000
#define D 128
#define NSHARD 8
#define SLOTS 48                       // per (node,shard); P(overflow) ~ 3e-16
#define NODE_STRIDE (NSHARD * SLOTS)   // 384 ushorts per node

typedef __attribute__((ext_vector_type(8))) short bf16x8;
typedef __attribute__((ext_vector_type(4))) float f32x4;

// ws layout (int units):
//   edge_src : 10000*384 ushort = 1,920,000 ints (7.68 MB)
//   cnt      : 8 x 10000        =    80,000 ints
//   y        : 1.28M bf16       =   640,000 ints (y = x @ W^T, bf16)
// total 2,640,000 ints = 10.56 MB (ws ~268 MB; garbage-index gathers up to
// y+16.8 MB stay far inside ws)
#define WS_EDGESRC 0
#define WS_CNT     1920000
#define WS_Y       2000000

__device__ __forceinline__ unsigned bf16_rtne(unsigned u) {
    return (u + 0x7fffu + ((u >> 16) & 1u)) >> 16;
}
__device__ __forceinline__ float blo(unsigned v) { return __uint_as_float(v << 16); }
__device__ __forceinline__ float bhi(unsigned v) { return __uint_as_float(v & 0xffff0000u); }

// ---------------------------------------------------------------------------
// Kernel 1: y = x @ W^T (bf16 MFMA, fp32 inputs converted inline) + zero cnt.
// 157 blocks x 256 threads; wave = 16 nodes x 128 outputs, 4 K-steps x 8
// o-tiles of v_mfma_f32_16x16x32_bf16. W (fp32) staged->bf16 in LDS stride 136.
// D-layout: row(node)=quad*4+reg, col(o)=lane&15 [m89-verified].
// Aggregation commutes with the linear map, so projecting FIRST lets the
// gather kernel sum y-rows straight into the output (bias added there).
// ---------------------------------------------------------------------------
#define WLD 136
__global__ __launch_bounds__(256) void gemm_y_kernel(
    const float* __restrict__ x,       // [N_NODES][128] fp32
    const float* __restrict__ W,       // [128][128] fp32
    unsigned short* __restrict__ y,    // [N_NODES][128] bf16
    int* __restrict__ cnt) {
    __shared__ __align__(16) unsigned short Wl[D * WLD];   // 34.8 KB

    int t = threadIdx.x;

    // zero the scatter counters (157*256*2 = 80384 >= 80000)
    {
        int g = (blockIdx.x * 256 + t) * 2;
        if (g < NSHARD * N_NODES) { cnt[g] = 0; cnt[g + 1] = 0; }
    }

    // stage W: fp32 -> bf16 -> LDS (8192 float-pairs)
    {
        const uint2* W2 = (const uint2*)W;
        #pragma unroll
        for (int u = t; u < 8192; u += 256) {
            uint2 w = W2[u];
            unsigned p = bf16_rtne(w.x) | (bf16_rtne(w.y) << 16);
            int row = u >> 6;
            int c2  = u & 63;
            *(unsigned*)&Wl[row * WLD + c2 * 2] = p;
        }
    }
    __syncthreads();

    int wave = t >> 6;
    int lane = t & 63;
    int l16  = lane & 15;
    int quad = lane >> 4;

    int m0 = blockIdx.x * 64 + wave * 16;
    int anode = m0 + l16;
    if (anode >= N_NODES) anode = N_NODES - 1;   // clamp loads; stores guarded

    f32x4 acc[8];
    #pragma unroll
    for (int i = 0; i < 8; ++i) acc[i] = (f32x4){0.f, 0.f, 0.f, 0.f};

    #pragma unroll
    for (int ks = 0; ks < 4; ++ks) {
        const uint4* ap = (const uint4*)(x + anode * D + ks * 32 + quad * 8);
        uint4 a0 = ap[0];
        uint4 a1 = ap[1];
        union { unsigned u[4]; bf16x8 v; } af;
        af.u[0] = bf16_rtne(a0.x) | (bf16_rtne(a0.y) << 16);
        af.u[1] = bf16_rtne(a0.z) | (bf16_rtne(a0.w) << 16);
        af.u[2] = bf16_rtne(a1.x) | (bf16_rtne(a1.y) << 16);
        af.u[3] = bf16_rtne(a1.z) | (bf16_rtne(a1.w) << 16);
        #pragma unroll
        for (int ot = 0; ot < 8; ++ot) {
            bf16x8 bf = *(const bf16x8*)&Wl[(ot * 16 + l16) * WLD + ks * 32 + quad * 8];
            acc[ot] = __builtin_amdgcn_mfma_f32_16x16x32_bf16(af.v, bf, acc[ot], 0, 0, 0);
        }
    }

    #pragma unroll
    for (int ot = 0; ot < 8; ++ot) {
        int o = ot * 16 + l16;
        #pragma unroll
        for (int r = 0; r < 4; ++r) {
            int node = m0 + quad * 4 + r;
            if (node < N_NODES)
                y[node * D + o] = (unsigned short)bf16_rtne(__float_as_uint(acc[ot][r]));
        }
    }
}

// ---------------------------------------------------------------------------
// Kernel 2: single-pass padded bucket scatter, 1 edge/thread (2500 blocks ->
// ~32 waves/CU of atomic-latency hiding). shard = blockIdx & 7 (XCD-local).
// ---------------------------------------------------------------------------
__global__ __launch_bounds__(256) void scatter_kernel(const int* __restrict__ src,
                                                      const int* __restrict__ dst,
                                                      int* __restrict__ cnt,
                                                      unsigned short* __restrict__ edge_src) {
    int i = blockIdx.x * 256 + threadIdx.x;          // 640000 threads exactly
    int s = src[i];
    int d = dst[i];
    int sh = blockIdx.x & (NSHARD - 1);
    int p = atomicAdd(&cnt[sh * N_NODES + d], 1);
    if (p < SLOTS) edge_src[d * NODE_STRIDE + sh * SLOTS + p] = (unsigned short)s;
}

// ---------------------------------------------------------------------------
// Kernel 3: out[n] = b + sum_{neighbors} y[s]  (bf16 rows, fp32 accumulate).
// Quarter-wave (16 lanes) per node, uint4 = 8 bf16 per lane = full 256 B row.
// Dual-stream predicated batches: shards sp and sp+4 processed concurrently
// -> 16 outstanding dwordx4 gathers per lane. No LDS, no barrier.
// Unwritten/padded slots read poison (<=0xFFFF): gather lands < ws end, and
// the mask zeroes it. 625 blocks x 16 nodes exactly.
// ---------------------------------------------------------------------------
__global__ __launch_bounds__(256) void agg_kernel(
    const uint4* __restrict__ y4,                // [N_NODES][16] uint4
    const unsigned short* __restrict__ edge_src, // [N_NODES][8][48]
    const int* __restrict__ cnt,                 // [8][N_NODES]
    const float* __restrict__ b,
    float4* __restrict__ out4) {                 // [N_NODES][32] float4
    int t = threadIdx.x;
    int q = t >> 4;                  // node slot 0..15
    int l = t & 15;                  // col group (8 bf16 = 32 B of fp32 out)
    int n = blockIdx.x * 16 + q;

    float acc[8];
    #pragma unroll
    for (int i = 0; i < 8; ++i) acc[i] = 0.f;

    #pragma unroll
    for (int sp = 0; sp < 4; ++sp) {
        int cA = cnt[sp * N_NODES + n];
        int cB = cnt[(sp + 4) * N_NODES + n];
        if (cA > SLOTS) cA = SLOTS;
        if (cB > SLOTS) cB = SLOTS;
        const unsigned short* segA = edge_src + n * NODE_STRIDE + sp * SLOTS;
        const unsigned short* segB = edge_src + n * NODE_STRIDE + (sp + 4) * SLOTS;
        int nb = cA > cB ? cA : cB;
        for (int j = 0; j < nb; j += 8) {
            uint4 siA = *(const uint4*)(segA + j);   // j<=40, j+8<=48: in bounds
            uint4 siB = *(const uint4*)(segB + j);
            unsigned iA[8], iB[8];
            iA[0] = siA.x & 0xffffu; iA[1] = siA.x >> 16;
            iA[2] = siA.y & 0xffffu; iA[3] = siA.y >> 16;
            iA[4] = siA.z & 0xffffu; iA[5] = siA.z >> 16;
            iA[6] = siA.w & 0xffffu; iA[7] = siA.w >> 16;
            iB[0] = siB.x & 0xffffu; iB[1] = siB.x >> 16;
            iB[2] = siB.y & 0xffffu; iB[3] = siB.y >> 16;
            iB[4] = siB.z & 0xffffu; iB[5] = siB.z >> 16;
            iB[6] = siB.w & 0xffffu; iB[7] = siB.w >> 16;
            #pragma unroll
            for (int u = 0; u < 8; ++u) {
                unsigned mA = (j + u < cA) ? 0xffffffffu : 0u;
                unsigned mB = (j + u < cB) ? 0xffffffffu : 0u;
                uint4 vA = y4[iA[u] * 16 + l];
                uint4 vB = y4[iB[u] * 16 + l];
                vA.x &= mA; vA.y &= mA; vA.z &= mA; vA.w &= mA;
                vB.x &= mB; vB.y &= mB; vB.z &= mB; vB.w &= mB;
                acc[0] += blo(vA.x) + blo(vB.x); acc[1] += bhi(vA.x) + bhi(vB.x);
                acc[2] += blo(vA.y) + blo(vB.y); acc[3] += bhi(vA.y) + bhi(vB.y);
                acc[4] += blo(vA.z) + blo(vB.z); acc[5] += bhi(vA.z) + bhi(vB.z);
                acc[6] += blo(vA.w) + blo(vB.w); acc[7] += bhi(vA.w) + bhi(vB.w);
            }
        }
    }

    const float4* b4 = (const float4*)b;
    float4 b0 = b4[l * 2], b1 = b4[l * 2 + 1];
    out4[n * 32 + l * 2]     = make_float4(acc[0] + b0.x, acc[1] + b0.y,
                                           acc[2] + b0.z, acc[3] + b0.w);
    out4[n * 32 + l * 2 + 1] = make_float4(acc[4] + b1.x, acc[5] + b1.y,
                                           acc[6] + b1.z, acc[7] + b1.w);
}

// ---------------------------------------------------------------------------
extern "C" void kernel_launch(void* const* d_in, const int* in_sizes, int n_in,
                              void* d_out, int out_size, void* d_ws, size_t ws_size,
                              hipStream_t stream) {
    const float* x   = (const float*)d_in[0];
    const int*   src = (const int*)  d_in[1];
    const int*   dst = (const int*)  d_in[2];
    const float* W   = (const float*)d_in[3];
    const float* b   = (const float*)d_in[4];
    float* out = (float*)d_out;

    int* wsI = (int*)d_ws;
    unsigned short* edge_src = (unsigned short*)(wsI + WS_EDGESRC);
    int* cnt = wsI + WS_CNT;
    unsigned short* y = (unsigned short*)(wsI + WS_Y);

    // 1) y = x @ W^T (bf16 MFMA) + zero cnt
    gemm_y_kernel<<<(N_NODES + 63) / 64, 256, 0, stream>>>(x, W, y, cnt);

    // 2) padded bucket scatter, 1 edge/thread
    scatter_kernel<<<N_EDGES / 256, 256, 0, stream>>>(src, dst, cnt, edge_src);

    // 3) aggregate y rows + bias -> out
    agg_kernel<<<N_NODES / 16, 256, 0, stream>>>(
        (const uint4*)y, edge_src, cnt, b, (float4*)out);
}

// Round 10
// 117.213 us; speedup vs baseline: 1.0483x; 1.0483x over previous
//
#include <hip/hip_runtime.h>

#define N_NODES 10000
#define N_EDGES 640000
#define D 128
#define NSHARD 8
#define SLOTS 64                       // 64 ushorts = 128 B = ONE cache line per
                                       // (node,shard): no cross-XCD false sharing
#define NODE_STRIDE (NSHARD * SLOTS)   // 512 ushorts = 1 KB per node

typedef __attribute__((ext_vector_type(8))) short bf16x8;
typedef __attribute__((ext_vector_type(4))) float f32x4;

// ws layout (int units):
//   edge_src : 10000*512 ushort = 2,560,000 ints (10.24 MB)
//   cnt      : 8 x 10000        =    80,000 ints
//   y        : 1.28M bf16       =   640,000 ints (y = x @ W^T, bf16)
// total 3,280,000 ints = 13.1 MB (ws ~268 MB; poison-index gathers from y
// reach at most ~22 MB into ws — safe)
#define WS_EDGESRC 0
#define WS_CNT     2560000
#define WS_Y       2640000

#define GEMM_BLOCKS 157                // ceil(10000/64)
#define SCAT_BLOCKS (N_EDGES / 256)    // 2500

__device__ __forceinline__ unsigned bf16_rtne(unsigned u) {
    return (u + 0x7fffu + ((u >> 16) & 1u)) >> 16;
}
__device__ __forceinline__ float blo(unsigned v) { return __uint_as_float(v << 16); }
__device__ __forceinline__ float bhi(unsigned v) { return __uint_as_float(v & 0xffff0000u); }

// ---------------------------------------------------------------------------
// Mega-kernel: blocks [0,157) compute y = x @ W^T (bf16 MFMA); blocks
// [157, 2657) do the padded bucket scatter. The two jobs are independent;
// fusing them lets scatter's atomic-latency waves overlap gemm's MFMA waves
// on the same CUs instead of serializing as two dispatches.
// cnt must be zeroed BEFORE this kernel (hipMemsetAsync) since scatter blocks
// may run before any gemm block.
// ---------------------------------------------------------------------------
#define WLD 136
__global__ __launch_bounds__(256) void fused_gemm_scatter_kernel(
    const float* __restrict__ x,       // [N_NODES][128] fp32
    const float* __restrict__ W,       // [128][128] fp32
    const int* __restrict__ src,
    const int* __restrict__ dst,
    int* __restrict__ cnt,             // [8][N_NODES], pre-zeroed
    unsigned short* __restrict__ edge_src,
    unsigned short* __restrict__ y) {  // [N_NODES][128] bf16
    __shared__ __align__(16) unsigned short Wl[D * WLD];   // 34.8 KB

    int t = threadIdx.x;

    if (blockIdx.x >= GEMM_BLOCKS) {
        // ---------------- scatter part: 1 edge/thread ----------------
        int bb = blockIdx.x - GEMM_BLOCKS;          // 0..2499
        int i = bb * 256 + t;                       // 640000 threads exactly
        int s = src[i];
        int d = dst[i];
        int sh = bb & (NSHARD - 1);
        int p = atomicAdd(&cnt[sh * N_NODES + d], 1);
        if (p < SLOTS)
            edge_src[d * NODE_STRIDE + sh * SLOTS + p] = (unsigned short)s;
        return;
    }

    // ---------------- gemm part: y = x @ W^T ----------------
    // stage W: fp32 -> bf16 -> LDS (8192 float-pairs), stride 136 shorts
    {
        const uint2* W2 = (const uint2*)W;
        #pragma unroll
        for (int u = t; u < 8192; u += 256) {
            uint2 w = W2[u];
            unsigned p = bf16_rtne(w.x) | (bf16_rtne(w.y) << 16);
            int row = u >> 6;
            int c2  = u & 63;
            *(unsigned*)&Wl[row * WLD + c2 * 2] = p;
        }
    }
    __syncthreads();

    int wave = t >> 6;
    int lane = t & 63;
    int l16  = lane & 15;
    int quad = lane >> 4;

    int m0 = blockIdx.x * 64 + wave * 16;
    int anode = m0 + l16;
    if (anode >= N_NODES) anode = N_NODES - 1;   // clamp loads; stores guarded

    f32x4 acc[8];
    #pragma unroll
    for (int i = 0; i < 8; ++i) acc[i] = (f32x4){0.f, 0.f, 0.f, 0.f};

    #pragma unroll
    for (int ks = 0; ks < 4; ++ks) {
        const uint4* ap = (const uint4*)(x + anode * D + ks * 32 + quad * 8);
        uint4 a0 = ap[0];
        uint4 a1 = ap[1];
        union { unsigned u[4]; bf16x8 v; } af;
        af.u[0] = bf16_rtne(a0.x) | (bf16_rtne(a0.y) << 16);
        af.u[1] = bf16_rtne(a0.z) | (bf16_rtne(a0.w) << 16);
        af.u[2] = bf16_rtne(a1.x) | (bf16_rtne(a1.y) << 16);
        af.u[3] = bf16_rtne(a1.z) | (bf16_rtne(a1.w) << 16);
        #pragma unroll
        for (int ot = 0; ot < 8; ++ot) {
            bf16x8 bf = *(const bf16x8*)&Wl[(ot * 16 + l16) * WLD + ks * 32 + quad * 8];
            acc[ot] = __builtin_amdgcn_mfma_f32_16x16x32_bf16(af.v, bf, acc[ot], 0, 0, 0);
        }
    }

    #pragma unroll
    for (int ot = 0; ot < 8; ++ot) {
        int o = ot * 16 + l16;
        #pragma unroll
        for (int r = 0; r < 4; ++r) {
            int node = m0 + quad * 4 + r;
            if (node < N_NODES)
                y[node * D + o] = (unsigned short)bf16_rtne(__float_as_uint(acc[ot][r]));
        }
    }
}

// ---------------------------------------------------------------------------
// Aggregation: out[n] = b + sum_{neighbors} y[s]  (bf16 rows, fp32 accum).
// Quarter-wave (16 lanes) per node; lane = uint4 = 8 bf16 (full 256 B row per
// quarter-wave, coalesced: all 16 lanes read the same y row). Dual-stream
// predicated batches (shards sp / sp+4) -> up to 16 outstanding dwordx4.
// Poison/unwritten slots (0xAAAA) gather from inside ws and are masked to 0.
// ---------------------------------------------------------------------------
__global__ __launch_bounds__(256) void agg_kernel(
    const uint4* __restrict__ y4,                // [N_NODES][16] uint4
    const unsigned short* __restrict__ edge_src, // [N_NODES][8][64]
    const int* __restrict__ cnt,                 // [8][N_NODES]
    const float* __restrict__ b,
    float4* __restrict__ out4) {                 // [N_NODES][32] float4
    int t = threadIdx.x;
    int q = t >> 4;                  // node slot 0..15
    int l = t & 15;                  // col group (8 bf16 = 32 B of fp32 out)
    int n = blockIdx.x * 16 + q;

    float acc[8];
    #pragma unroll
    for (int i = 0; i < 8; ++i) acc[i] = 0.f;

    #pragma unroll
    for (int sp = 0; sp < 4; ++sp) {
        int cA = cnt[sp * N_NODES + n];
        int cB = cnt[(sp + 4) * N_NODES + n];
        if (cA > SLOTS) cA = SLOTS;
        if (cB > SLOTS) cB = SLOTS;
        const unsigned short* segA = edge_src + n * NODE_STRIDE + sp * SLOTS;
        const unsigned short* segB = edge_src + n * NODE_STRIDE + (sp + 4) * SLOTS;
        int nb = cA > cB ? cA : cB;
        for (int j = 0; j < nb; j += 8) {
            uint4 siA = *(const uint4*)(segA + j);   // j<=56, j+8<=64: in bounds
            uint4 siB = *(const uint4*)(segB + j);
            unsigned iA[8], iB[8];
            iA[0] = siA.x & 0xffffu; iA[1] = siA.x >> 16;
            iA[2] = siA.y & 0xffffu; iA[3] = siA.y >> 16;
            iA[4] = siA.z & 0xffffu; iA[5] = siA.z >> 16;
            iA[6] = siA.w & 0xffffu; iA[7] = siA.w >> 16;
            iB[0] = siB.x & 0xffffu; iB[1] = siB.x >> 16;
            iB[2] = siB.y & 0xffffu; iB[3] = siB.y >> 16;
            iB[4] = siB.z & 0xffffu; iB[5] = siB.z >> 16;
            iB[6] = siB.w & 0xffffu; iB[7] = siB.w >> 16;
            #pragma unroll
            for (int u = 0; u < 8; ++u) {
                unsigned mA = (j + u < cA) ? 0xffffffffu : 0u;
                unsigned mB = (j + u < cB) ? 0xffffffffu : 0u;
                uint4 vA = y4[iA[u] * 16 + l];
                uint4 vB = y4[iB[u] * 16 + l];
                vA.x &= mA; vA.y &= mA; vA.z &= mA; vA.w &= mA;
                vB.x &= mB; vB.y &= mB; vB.z &= mB; vB.w &= mB;
                acc[0] += blo(vA.x) + blo(vB.x); acc[1] += bhi(vA.x) + bhi(vB.x);
                acc[2] += blo(vA.y) + blo(vB.y); acc[3] += bhi(vA.y) + bhi(vB.y);
                acc[4] += blo(vA.z) + blo(vB.z); acc[5] += bhi(vA.z) + bhi(vB.z);
                acc[6] += blo(vA.w) + blo(vB.w); acc[7] += bhi(vA.w) + bhi(vB.w);
            }
        }
    }

    const float4* b4 = (const float4*)b;
    float4 b0 = b4[l * 2], b1 = b4[l * 2 + 1];
    out4[n * 32 + l * 2]     = make_float4(acc[0] + b0.x, acc[1] + b0.y,
                                           acc[2] + b0.z, acc[3] + b0.w);
    out4[n * 32 + l * 2 + 1] = make_float4(acc[4] + b1.x, acc[5] + b1.y,
                                           acc[6] + b1.z, acc[7] + b1.w);
}

// ---------------------------------------------------------------------------
extern "C" void kernel_launch(void* const* d_in, const int* in_sizes, int n_in,
                              void* d_out, int out_size, void* d_ws, size_t ws_size,
                              hipStream_t stream) {
    const float* x   = (const float*)d_in[0];
    const int*   src = (const int*)  d_in[1];
    const int*   dst = (const int*)  d_in[2];
    const float* W   = (const float*)d_in[3];
    const float* b   = (const float*)d_in[4];
    float* out = (float*)d_out;

    int* wsI = (int*)d_ws;
    unsigned short* edge_src = (unsigned short*)(wsI + WS_EDGESRC);
    int* cnt = wsI + WS_CNT;
    unsigned short* y = (unsigned short*)(wsI + WS_Y);

    // 1) zero scatter counters (must precede the fused kernel: scatter blocks
    //    may execute before any gemm block)
    hipMemsetAsync(cnt, 0, NSHARD * N_NODES * sizeof(int), stream);

    // 2) fused: y = x @ W^T (blocks 0..156) + bucket scatter (blocks 157..2656)
    fused_gemm_scatter_kernel<<<GEMM_BLOCKS + SCAT_BLOCKS, 256, 0, stream>>>(
        x, W, src, dst, cnt, edge_src, y);

    // 3) aggregate y rows + bias -> out
    agg_kernel<<<N_NODES / 16, 256, 0, stream>>>(
        (const uint4*)y, edge_src, cnt, b, (float4*)out);
}

// Round 11
// 113.781 us; speedup vs baseline: 1.0799x; 1.0302x over previous
//
#include <hip/hip_runtime.h>

#define N_NODES 10000
#define N_EDGES 640000
#define D 128
#define NSHARD 8
#define SLOTS 64                       // 64 ushorts = 128 B = ONE cache line per
                                       // (node,shard): no cross-XCD false sharing
#define NODE_STRIDE (NSHARD * SLOTS)   // 512 ushorts = 1 KB per node

typedef __attribute__((ext_vector_type(8))) short bf16x8;
typedef __attribute__((ext_vector_type(4))) float f32x4;

// ws layout (int units):
//   edge_src : 10000*512 ushort = 2,560,000 ints (10.24 MB)
//   cnt      : 8 x 10000        =    80,000 ints
//   y        : 1.28M bf16       =   640,000 ints (y = x @ W^T, bf16)
#define WS_EDGESRC 0
#define WS_CNT     2560000
#define WS_Y       2640000

#define GEMM_BLOCKS 157                // ceil(10000/64)
#define SCAT_BLOCKS (N_EDGES / 256)    // 2500

__device__ __forceinline__ unsigned bf16_rtne(unsigned u) {
    return (u + 0x7fffu + ((u >> 16) & 1u)) >> 16;
}
__device__ __forceinline__ float blo(unsigned v) { return __uint_as_float(v << 16); }
__device__ __forceinline__ float bhi(unsigned v) { return __uint_as_float(v & 0xffff0000u); }

// ---------------------------------------------------------------------------
// Mega-kernel (UNCHANGED from R10): blocks [0,157) compute y = x @ W^T (bf16
// MFMA); blocks [157, 2657) do the padded bucket scatter.
// ---------------------------------------------------------------------------
#define WLD 136
__global__ __launch_bounds__(256) void fused_gemm_scatter_kernel(
    const float* __restrict__ x,
    const float* __restrict__ W,
    const int* __restrict__ src,
    const int* __restrict__ dst,
    int* __restrict__ cnt,             // pre-zeroed
    unsigned short* __restrict__ edge_src,
    unsigned short* __restrict__ y) {
    __shared__ __align__(16) unsigned short Wl[D * WLD];   // 34.8 KB

    int t = threadIdx.x;

    if (blockIdx.x >= GEMM_BLOCKS) {
        int bb = blockIdx.x - GEMM_BLOCKS;
        int i = bb * 256 + t;
        int s = src[i];
        int d = dst[i];
        int sh = bb & (NSHARD - 1);
        int p = atomicAdd(&cnt[sh * N_NODES + d], 1);
        if (p < SLOTS)
            edge_src[d * NODE_STRIDE + sh * SLOTS + p] = (unsigned short)s;
        return;
    }

    {
        const uint2* W2 = (const uint2*)W;
        #pragma unroll
        for (int u = t; u < 8192; u += 256) {
            uint2 w = W2[u];
            unsigned p = bf16_rtne(w.x) | (bf16_rtne(w.y) << 16);
            int row = u >> 6;
            int c2  = u & 63;
            *(unsigned*)&Wl[row * WLD + c2 * 2] = p;
        }
    }
    __syncthreads();

    int wave = t >> 6;
    int lane = t & 63;
    int l16  = lane & 15;
    int quad = lane >> 4;

    int m0 = blockIdx.x * 64 + wave * 16;
    int anode = m0 + l16;
    if (anode >= N_NODES) anode = N_NODES - 1;

    f32x4 acc[8];
    #pragma unroll
    for (int i = 0; i < 8; ++i) acc[i] = (f32x4){0.f, 0.f, 0.f, 0.f};

    #pragma unroll
    for (int ks = 0; ks < 4; ++ks) {
        const uint4* ap = (const uint4*)(x + anode * D + ks * 32 + quad * 8);
        uint4 a0 = ap[0];
        uint4 a1 = ap[1];
        union { unsigned u[4]; bf16x8 v; } af;
        af.u[0] = bf16_rtne(a0.x) | (bf16_rtne(a0.y) << 16);
        af.u[1] = bf16_rtne(a0.z) | (bf16_rtne(a0.w) << 16);
        af.u[2] = bf16_rtne(a1.x) | (bf16_rtne(a1.y) << 16);
        af.u[3] = bf16_rtne(a1.z) | (bf16_rtne(a1.w) << 16);
        #pragma unroll
        for (int ot = 0; ot < 8; ++ot) {
            bf16x8 bf = *(const bf16x8*)&Wl[(ot * 16 + l16) * WLD + ks * 32 + quad * 8];
            acc[ot] = __builtin_amdgcn_mfma_f32_16x16x32_bf16(af.v, bf, acc[ot], 0, 0, 0);
        }
    }

    #pragma unroll
    for (int ot = 0; ot < 8; ++ot) {
        int o = ot * 16 + l16;
        #pragma unroll
        for (int r = 0; r < 4; ++r) {
            int node = m0 + quad * 4 + r;
            if (node < N_NODES)
                y[node * D + o] = (unsigned short)bf16_rtne(__float_as_uint(acc[ot][r]));
        }
    }
}

// ---------------------------------------------------------------------------
// Aggregation v2: one quarter-wave per (node, shard-pair). Block = 256 thr =
// 16 quarter-waves = 4 nodes x 4 shard-pairs; 2500 blocks (4x R10's 625 ->
// ~10 blocks/CU of latency hiding instead of 2.4).
// Each quarter-wave: dual-stream predicated batches over shards {p, p+4}
// (up to 16 outstanding dwordx4). Partials (fp32) -> LDS with lane stride
// 9 floats (coprime with 32 banks -> 2-way max, free); shard-pair 0's
// quarter-wave combines 4 partials, adds bias, stores.
// ---------------------------------------------------------------------------
__global__ __launch_bounds__(256) void agg_kernel(
    const uint4* __restrict__ y4,                // [N_NODES][16] uint4
    const unsigned short* __restrict__ edge_src, // [N_NODES][8][64]
    const int* __restrict__ cnt,                 // [8][N_NODES]
    const float* __restrict__ b,
    float4* __restrict__ out4) {                 // [N_NODES][32] float4
    __shared__ float part[16 * 16 * 9];          // 9.2 KB, stride-9 padded

    int t = threadIdx.x;
    int qw = t >> 4;                 // 0..15
    int l  = t & 15;                 // col group (8 bf16 = 32 B fp32 out)
    int m  = qw & 3;                 // node slot 0..3
    int p  = qw >> 2;                // shard-pair 0..3
    int n  = blockIdx.x * 4 + m;     // 2500 blocks x 4 nodes = 10000 exactly

    float acc[8];
    #pragma unroll
    for (int i = 0; i < 8; ++i) acc[i] = 0.f;

    int cA = cnt[p * N_NODES + n];
    int cB = cnt[(p + 4) * N_NODES + n];
    if (cA > SLOTS) cA = SLOTS;
    if (cB > SLOTS) cB = SLOTS;
    const unsigned short* segA = edge_src + n * NODE_STRIDE + p * SLOTS;
    const unsigned short* segB = edge_src + n * NODE_STRIDE + (p + 4) * SLOTS;
    int nb = cA > cB ? cA : cB;

    for (int j = 0; j < nb; j += 8) {
        uint4 siA = *(const uint4*)(segA + j);   // 16B-aligned, j+8 <= 64
        uint4 siB = *(const uint4*)(segB + j);
        unsigned iA[8], iB[8];
        iA[0] = siA.x & 0xffffu; iA[1] = siA.x >> 16;
        iA[2] = siA.y & 0xffffu; iA[3] = siA.y >> 16;
        iA[4] = siA.z & 0xffffu; iA[5] = siA.z >> 16;
        iA[6] = siA.w & 0xffffu; iA[7] = siA.w >> 16;
        iB[0] = siB.x & 0xffffu; iB[1] = siB.x >> 16;
        iB[2] = siB.y & 0xffffu; iB[3] = siB.y >> 16;
        iB[4] = siB.z & 0xffffu; iB[5] = siB.z >> 16;
        iB[6] = siB.w & 0xffffu; iB[7] = siB.w >> 16;
        #pragma unroll
        for (int u = 0; u < 8; ++u) {
            unsigned mA = (j + u < cA) ? 0xffffffffu : 0u;
            unsigned mB = (j + u < cB) ? 0xffffffffu : 0u;
            uint4 vA = y4[iA[u] * 16 + l];       // poison idx stays inside ws
            uint4 vB = y4[iB[u] * 16 + l];
            vA.x &= mA; vA.y &= mA; vA.z &= mA; vA.w &= mA;
            vB.x &= mB; vB.y &= mB; vB.z &= mB; vB.w &= mB;
            acc[0] += blo(vA.x) + blo(vB.x); acc[1] += bhi(vA.x) + bhi(vB.x);
            acc[2] += blo(vA.y) + blo(vB.y); acc[3] += bhi(vA.y) + bhi(vB.y);
            acc[4] += blo(vA.z) + blo(vB.z); acc[5] += bhi(vA.z) + bhi(vB.z);
            acc[6] += blo(vA.w) + blo(vB.w); acc[7] += bhi(vA.w) + bhi(vB.w);
        }
    }

    // partials -> LDS (lane-linear stride 9 -> conflict-free)
    {
        float* pr = &part[(qw * 16 + l) * 9];
        #pragma unroll
        for (int k = 0; k < 8; ++k) pr[k] = acc[k];
    }
    __syncthreads();

    if (p == 0) {
        #pragma unroll
        for (int p2 = 1; p2 < 4; ++p2) {
            const float* pr = &part[(((p2 << 2) | m) * 16 + l) * 9];
            #pragma unroll
            for (int k = 0; k < 8; ++k) acc[k] += pr[k];
        }
        const float4* b4 = (const float4*)b;
        float4 b0 = b4[l * 2], b1 = b4[l * 2 + 1];
        out4[n * 32 + l * 2]     = make_float4(acc[0] + b0.x, acc[1] + b0.y,
                                               acc[2] + b0.z, acc[3] + b0.w);
        out4[n * 32 + l * 2 + 1] = make_float4(acc[4] + b1.x, acc[5] + b1.y,
                                               acc[6] + b1.z, acc[7] + b1.w);
    }
}

// ---------------------------------------------------------------------------
extern "C" void kernel_launch(void* const* d_in, const int* in_sizes, int n_in,
                              void* d_out, int out_size, void* d_ws, size_t ws_size,
                              hipStream_t stream) {
    const float* x   = (const float*)d_in[0];
    const int*   src = (const int*)  d_in[1];
    const int*   dst = (const int*)  d_in[2];
    const float* W   = (const float*)d_in[3];
    const float* b   = (const float*)d_in[4];
    float* out = (float*)d_out;

    int* wsI = (int*)d_ws;
    unsigned short* edge_src = (unsigned short*)(wsI + WS_EDGESRC);
    int* cnt = wsI + WS_CNT;
    unsigned short* y = (unsigned short*)(wsI + WS_Y);

    // 1) zero scatter counters
    hipMemsetAsync(cnt, 0, NSHARD * N_NODES * sizeof(int), stream);

    // 2) fused: y = x @ W^T (blocks 0..156) + bucket scatter (blocks 157..2656)
    fused_gemm_scatter_kernel<<<GEMM_BLOCKS + SCAT_BLOCKS, 256, 0, stream>>>(
        x, W, src, dst, cnt, edge_src, y);

    // 3) aggregate v2: quarter-wave per (node, shard-pair)
    agg_kernel<<<N_NODES / 4, 256, 0, stream>>>(
        (const uint4*)y, edge_src, cnt, b, (float4*)out);
}